// Round 7
// baseline (2003.405 us; speedup 1.0000x reference)
//
#include <hip/hip_runtime.h>
#include <cstddef>
#include <cstdint>

// CT-LSTM right-to-left scan, weight-stationary MFMA, 4-cohort rotation.
// 128 seqs (B=16,P=8), T=256, H=256, 7H=1792 gate rows, VOCAB=35, IDX_PAD=34.
//
//   z = EW[event]  +  h @ W2^T        (W2 = W[:,256:512], f16)
//
// 2 supergroups x 16 slices = 32 blocks. Block (b,p) holds B-fragments for
// hidden j in [16b,16b+16) resident in VGPRs and rotates FOUR cohorts of 16
// seqs (quarters q = 4*it + c). Depth-4 rotation puts >=1 full quarter of
// slack on every cross-block dependency:
//   - h loads issued 2 quarters before use (flight ~2000cy >> L3 RT)
//   - flag released 1 quarter after publish (pub-ack certified by the
//     counted top-of-quarter wait, not by a drain)
//   - probe issued 1 quarter before its spin -> spin = register compare
//
// Per-wave per-quarter VMEM order is FIXED: [flag(w0 only), probe, pub,
// h x8, out x6] (16 ops; 17 for wave 0). One s_waitcnt vmcnt(14) at each
// quarter top therefore retires: this quarter's MFMA operands (issued 2
// quarters ago), the previous quarter's probe (spin value) and pub (-> its
// flag may be released now). It leaves prev's h x8 + out x6 (14) in flight.
// There is NO vmcnt(0) in the steady-state loop. Pub is UNconditional so the
// FIFO count stays uniform (the it=254 publish lands in a parity slot no one
// reads again; WAR margin >= 4 quarters).

typedef _Float16 hf;
typedef _Float16 f16x8 __attribute__((ext_vector_type(8)));
typedef float    f32x4 __attribute__((ext_vector_type(4)));

#define HID  256
#define R7   1792
#define TT   256
#define NPAD 34

__device__ __forceinline__ float sigf(float x) { return 1.0f / (1.0f + __expf(-x)); }
__device__ __forceinline__ float tanh_f(float x) { return 1.0f - 2.0f / (__expf(2.0f * x) + 1.0f); }
__device__ __forceinline__ float softplusf(float x) {
  return fmaxf(x, 0.0f) + __logf(1.0f + __expf(-fabsf(x)));
}

// ---------------------------------------------------------------------------
// Repack W[:,256:512] into MFMA B-fragment order.
// Entry idx = ((b*7+g)*8 + kt)*64 + lane:
//   B[k = kt*32 + 8*(lane>>4) + e][n = lane&15] = W2[g*256 + 16b + (lane&15)][k]
__global__ __launch_bounds__(256) void repack_mfma(const float* __restrict__ W,
                                                   f16x8* __restrict__ Wf) {
  int idx  = blockIdx.x * 256 + threadIdx.x;  // [0, 57344)
  int lane = idx & 63;
  int kt   = (idx >> 6) & 7;
  int gb   = idx >> 9;            // b*7 + g
  int g    = gb % 7;
  int b    = gb / 7;
  int row  = g * HID + b * 16 + (lane & 15);
  int k0   = kt * 32 + (lane >> 4) * 8;
  const float* src = W + (size_t)row * 512 + 256 + k0;
  f16x8 o;
#pragma unroll
  for (int e = 0; e < 8; ++e) o[e] = (hf)src[e];
  Wf[idx] = o;
}

// ---------------------------------------------------------------------------
// EW[e][r] = sum_k Emb[e][k] * W[r][k] + b[r]   (e<35, r<1792, k<256)
// Block-per-16-rows; Emb staged in LDS; W read exactly once (1.8 MB total).
__global__ __launch_bounds__(256) void ew_kernel(const float* __restrict__ Emb,
                                                 const float* __restrict__ W,
                                                 const float* __restrict__ bias,
                                                 float* __restrict__ EW) {
  __shared__ float embl[35 * 256];
  const int tid = threadIdx.x;
  for (int idx = tid; idx < 35 * 256; idx += 256) embl[idx] = Emb[idx];
  __syncthreads();
  const int wid = tid >> 6, lane = tid & 63;
  int r = blockIdx.x * 16 + wid * 4;
#pragma unroll
  for (int rr = 0; rr < 4; ++rr, ++r) {
    const float4 wv4 = *(const float4*)(W + (size_t)r * 512 + lane * 4);
    const float brr = bias[r];
    for (int e = 0; e < 35; ++e) {
      const float4 em = *(const float4*)(embl + e * 256 + lane * 4);
      float acc = wv4.x * em.x + wv4.y * em.y + wv4.z * em.z + wv4.w * em.w;
#pragma unroll
      for (int m = 32; m >= 1; m >>= 1) acc += __shfl_xor(acc, m, 64);
      if (lane == 0) EW[(size_t)e * R7 + r] = acc + brr;
    }
  }
}

// ---------------------------------------------------------------------------
__global__ __launch_bounds__(256, 1) void scan_mfma(
    const int* __restrict__ event, const float* __restrict__ dtime,
    const float* __restrict__ EW, const f16x8* __restrict__ Wf,
    hf* __restrict__ hbuf, int* __restrict__ flags,
    float* __restrict__ out) {
  const int tid = threadIdx.x;
  const int b   = blockIdx.x & 15;   // hidden slice
  const int p   = blockIdx.x >> 4;   // super-group 0..1
  const int j0  = b * 16;
  const int wid = tid >> 6, lane = tid & 63;
  const int seq = tid >> 4, jj = tid & 15;   // epilogue ownership (per cohort)
  const int j   = j0 + jj;
  const int q   = lane >> 4, nn = lane & 15; // MFMA C/D coords

  __shared__ uint8_t evs8[64][TT];           // [cohort*16+seq][i], VOCAB<256
  __shared__ float   dts[64][TT];
  __shared__ __align__(16) float gbuf[7][16][20];  // [gate][n][seq] (pad 20)
  __shared__ float   ews[35 * 7 * 17];       // EW slice [e][g][nn], pad 17

#pragma unroll 4
  for (int r = 0; r < 64; ++r) {
    evs8[r][tid] = (uint8_t)event[(size_t)(p * 64 + r) * TT + tid];
    dts[r][tid]  = dtime[(size_t)(p * 64 + r) * TT + tid];
  }
  // EW slice -> LDS (35 ev x 7 gates x our 16 columns = 15.7 KB, once).
  for (int idx = tid; idx < 35 * 112; idx += 256) {
    int e  = idx / 112, r = idx - e * 112;
    int g  = r >> 4, n2 = r & 15;
    ews[(e * 7 + g) * 17 + n2] = EW[(size_t)e * R7 + g * HID + j0 + n2];
  }

  // Resident B fragments: wave w owns gates {2w, 2w+1} (w==3: gate 6 only).
  const int  g0  = 2 * wid;
  const bool two = (wid < 3);
  f16x8 B0[8], B1[8];
  {
    const f16x8* wsrc = Wf + (size_t)((b * 7 + g0) * 8) * 64 + lane;
#pragma unroll
    for (int kt = 0; kt < 8; ++kt) B0[kt] = wsrc[kt * 64];
    if (two) {
#pragma unroll
      for (int kt = 0; kt < 8; ++kt) B1[kt] = wsrc[(8 + kt) * 64];
    }
  }
  // Retire ALL prologue VMEM before the counted-vmcnt loop begins.
  asm volatile("s_waitcnt vmcnt(0)" ::: "memory");
  __builtin_amdgcn_sched_barrier(0);
#pragma unroll
  for (int kt = 0; kt < 8; ++kt) {
    asm volatile("" :: "v"(B0[kt]));
    if (two) asm volatile("" :: "v"(B1[kt]));
  }
  __syncthreads();

  int* flp = flags + p * 64;                  // [cohort][16 ints]
  hf*  hpb = hbuf + (size_t)p * 8 * 4096;     // [cohort][parity][4096]

  // h' store offset in A-fragment order (same lane->k map as the reader).
  const int off16 = ((j >> 5) * 64 + seq + 16 * ((j >> 3) & 3)) * 8 + (j & 7);
  const size_t OS = 8355840;  // per-output-tensor stride

  float cp0 = 0.f, cb0 = 0.f, cp1 = 0.f, cb1 = 0.f;
  float cp2 = 0.f, cb2 = 0.f, cp3 = 0.f, cb3 = 0.f;
  f16x8 avE[8], avO[8];
#pragma unroll
  for (int kt = 0; kt < 8; ++kt) { avE[kt] = (f16x8)(hf)0.0f; avO[kt] = (f16x8)(hf)0.0f; }
  int pr = 0;  // probe value; re-defined by the top-of-quarter wait asm

  // Quarter q = 4*it + c. av set parity = c&1 (consume early, refill late).
  auto quarter = [&](const int c, const int it, f16x8 (&av)[8],
                     float& cp, float& cb) {
    const int i   = 255 - it;
    const int cs  = c * 16 + seq;
    const int c2  = (c + 2) & 3;                 // spin/load target cohort
    const int it2 = it + (c >= 2 ? 1 : 0);       // its iteration
    const int c3  = (c + 3) & 3;                 // release + probe cohort
    const int v1  = (c == 0) ? it : it + 1;      // flag value for pub(q-1)

    // ---- A: counted wait. Retires: av (issued q-2), prev probe, prev pub.
    // Leaves prev's h x8 + out x6 in flight. "+v"(pr): def-point after wait.
    asm volatile("s_waitcnt vmcnt(14)" : "+v"(pr) :: "memory");
    __builtin_amdgcn_sched_barrier(0);
    __builtin_amdgcn_s_barrier();   // all waves past wait; gbuf WAR-safe
    __builtin_amdgcn_sched_barrier(0);

    // ---- D: release flag for pub(q-1) (its ack was certified at A) ----
    if (tid == 0 && v1 > 0)
      asm volatile("global_store_dword %0, %1, off sc0 sc1"
                   :: "v"(flp + c3 * 16 + b), "v"(v1) : "memory");

    // ---- S: spin for (c2,it2) whose loads are issued at H below. The probe
    // (issued last quarter, targeting c2) was released >=1 quarter ago. ----
    if (it2 >= 1 && it2 <= 254) {
      int pv = (nn == b) ? 0x7fffffff : pr;
      if (!__all(pv >= it2)) {
        int gd = 0;
        const int* fp = flp + c2 * 16 + nn;
        for (;;) {
          int v;
          asm volatile("global_load_dword %0, %1, off sc0 sc1\n\t"
                       "s_waitcnt vmcnt(0)" : "=v"(v) : "v"(fp) : "memory");
          v = (nn == b) ? 0x7fffffff : v;
          if (__all(v >= it2) || ++gd > (1 << 20)) break;  // bail: fail, no hang
        }
      }
    }

    // ---- P: probe flags[c3] (spin value for NEXT quarter) ----
    asm volatile("global_load_dword %0, %1, off sc0 sc1"
                 : "=v"(pr) : "v"(flp + c3 * 16 + nn) : "memory");

    // ---- EW C-in gather (pure LDS) ----
    float e0[4], e1[4];
#pragma unroll
    for (int r = 0; r < 4; ++r) {
      const int evr  = evs8[c * 16 + 4 * q + r][i];
      const int base = (evr * 7 + g0) * 17 + nn;
      e0[r] = ews[base];
      e1[r] = two ? ews[base + 17] : 0.0f;
    }
    f32x4 acc0 = {e0[0], e0[1], e0[2], e0[3]};
    f32x4 acc1 = {e1[0], e1[1], e1[2], e1[3]};

    // ---- M: MFMA (av certified at A; flew ~2 quarters) ----
    if (it >= 1) {
#pragma unroll
      for (int kt = 0; kt < 8; ++kt) {
        acc0 = __builtin_amdgcn_mfma_f32_16x16x32_f16(av[kt], B0[kt], acc0, 0, 0, 0);
        if (two)
          acc1 = __builtin_amdgcn_mfma_f32_16x16x32_f16(av[kt], B1[kt], acc1, 0, 0, 0);
      }
    }

    // ---- G: gate exchange. C/D: lane l, reg r -> D[seq=4*(l>>4)+r][n=l&15]
    *(f32x4*)&gbuf[g0][nn][4 * q] = acc0;
    if (two) *(f32x4*)&gbuf[g0 + 1][nn][4 * q] = acc1;
    asm volatile("s_waitcnt lgkmcnt(0)" ::: "memory");
    __builtin_amdgcn_s_barrier();
    __builtin_amdgcn_sched_barrier(0);

    // ---- EP: epilogue for (seq, jj) — pure LDS+VALU ----
    const int   ev = evs8[cs][i];
    const float dt = dts[cs][i];
    float zz[7];
#pragma unroll
    for (int g = 0; g < 7; ++g) zz[g] = gbuf[g][jj][seq];
    float gi = sigf(zz[0]), gf = sigf(zz[1]), go = sigf(zz[2]);
    float gz = tanh_f(zz[3]);
    float gib = sigf(zz[4]), gfb = sigf(zz[5]);
    float gd = softplusf(zz[6]);
    float cell = gf * cp + gi * gz;
    float cbar = gfb * cb + gib * gz;
    float hm   = go * tanh_f(cell);
    float dec  = __expf(-gd * dt);
    float cim  = cbar + (cell - cbar) * dec;
    float him  = go * tanh_f(cim);
    float msk  = (ev != NPAD) ? 1.0f : 0.0f;
    float cbm  = cbar * msk;
    float hn   = him * msk;
    cp = cim * msk;
    cb = cbm;

    // ---- U: publish h' (UNconditional: uniform FIFO; it=254 lands in a
    // parity slot with >=4-quarter dead margin) ----
    {
      unsigned short hb16 = __builtin_bit_cast(unsigned short, (hf)hn);
      unsigned nb = __shfl_down((unsigned)hb16, 1, 64);
      if (!(jj & 1)) {
        unsigned pack = (unsigned)hb16 | (nb << 16);
        hf* hw = hpb + (size_t)(c * 2 + ((it + 1) & 1)) * 4096;
        asm volatile("global_store_dword %0, %1, off sc0 sc1"
                     :: "v"((unsigned*)(hw + off16)), "v"(pack) : "memory");
      }
    }

    // ---- H: issue h loads for (c2, it2); consumed 2 quarters from now ----
    {
      const int itc = (it2 > 254) ? 254 : it2;   // tail clamp (values unused)
      const hf* hp = hpb + (size_t)(c2 * 2 + (itc & 1)) * 4096 + (size_t)lane * 8;
#pragma unroll
      for (int kt = 0; kt < 8; ++kt)
        asm volatile("global_load_dwordx4 %0, %1, off sc0 sc1"
                     : "=v"(av[kt]) : "v"(hp + (size_t)kt * 512) : "memory");
    }

    // ---- O: outputs — newest 6 VMEM; float for a full quarter ----
    float* o = out + (size_t)(p * 64 + cs) * 65280 + (size_t)(i - 1) * HID + j;
    asm volatile("global_store_dword %0, %1, off" :: "v"(o), "v"(cell) : "memory");
    asm volatile("global_store_dword %0, %1, off" :: "v"(o + OS), "v"(cbm) : "memory");
    asm volatile("global_store_dword %0, %1, off" :: "v"(o + 2 * OS), "v"(gd) : "memory");
    asm volatile("global_store_dword %0, %1, off" :: "v"(o + 3 * OS), "v"(go) : "memory");
    asm volatile("global_store_dword %0, %1, off" :: "v"(o + 4 * OS), "v"(hn) : "memory");
    asm volatile("global_store_dword %0, %1, off" :: "v"(o + 5 * OS), "v"(hm) : "memory");
  };

#pragma unroll 1
  for (int it = 0; it < 255; ++it) {
    quarter(0, it, avE, cp0, cb0);
    quarter(1, it, avO, cp1, cb1);
    quarter(2, it, avE, cp2, cb2);
    quarter(3, it, avO, cp3, cb3);
  }
}

// ---------------------------------------------------------------------------
extern "C" void kernel_launch(void* const* d_in, const int* in_sizes, int n_in,
                              void* d_out, int out_size, void* d_ws, size_t ws_size,
                              hipStream_t stream) {
  const int*   event = (const int*)d_in[0];
  const float* dtime = (const float*)d_in[1];
  const float* Emb   = (const float*)d_in[2];
  const float* W     = (const float*)d_in[3];
  const float* bias  = (const float*)d_in[4];
  float*       out   = (float*)d_out;

  char*  ws = (char*)d_ws;
  f16x8* Wf = (f16x8*)ws;                               // 917504 B
  float* EW = (float*)(ws + 917504);                    // 250880 B
  hf*    hb = (hf*)(ws + 917504 + 250880);              // 2p*4c*2par*8KB = 131072 B
  int*   fl = (int*)(ws + 917504 + 250880 + 131072);    // 2p*4c*16 ints = 512 B

  // h buffers + flags must be zero each launch (graph replay re-runs this).
  hipMemsetAsync(ws + 917504 + 250880, 0, 131072 + 512, stream);
  repack_mfma<<<224, 256, 0, stream>>>(W, Wf);
  ew_kernel<<<112, 256, 0, stream>>>(Emb, W, bias, EW);
  scan_mfma<<<32, 256, 0, stream>>>(event, dtime, EW, Wf, hb, fl, out);
}